// Round 2
// baseline (218.994 us; speedup 1.0000x reference)
//
#include <hip/hip_runtime.h>

typedef __attribute__((ext_vector_type(4))) float  f32x4;
typedef __attribute__((ext_vector_type(8))) short  s16x8;
typedef __attribute__((ext_vector_type(4))) unsigned int u32x4;
typedef __attribute__((ext_vector_type(4))) unsigned short u16x4;

#define NB 8
#define NT 2048
#define NC 1024
#define NH 128
#define NM (NB * NT)

__device__ __forceinline__ unsigned short f2bf(float f) {
  union { float f; unsigned u; } v; v.f = f;
  unsigned r = v.u + 0x7FFFu + ((v.u >> 16) & 1u);  // RNE
  return (unsigned short)(r >> 16);
}
__device__ __forceinline__ unsigned pack2(float a, float b) {
  return (unsigned)f2bf(a) | ((unsigned)f2bf(b) << 16);
}
__device__ __forceinline__ f32x4 mfma16(s16x8 a, s16x8 b, f32x4 c) {
  return __builtin_amdgcn_mfma_f32_16x16x32_bf16(a, b, c, 0, 0, 0);
}

// ---------------- kernel 0: W -> bf16, transposed [3][128][1024], Wq pre-scaled
__global__ __launch_bounds__(256) void k_prep_w(
    const float* __restrict__ wq, const float* __restrict__ wk,
    const float* __restrict__ wv, unsigned short* __restrict__ wt3) {
  int id = blockIdx.x * 256 + threadIdx.x;   // 0 .. 3*131072-1
  int w = id >> 17;
  int r = id & 131071;
  int c = r & 1023;
  int h = r >> 10;
  const float* W = (w == 0) ? wq : (w == 1) ? wk : wv;
  float v = W[c * NH + h];
  if (w == 0) v *= 0.08838834764831845f;     // 1/sqrt(128) folded into Wq
  wt3[id] = f2bf(v);                          // coalesced 2B writes
}

// ---------------- kernel 1: q,k,v projections. BM=32, N=384, BK=64.
// x staged fp32->bf16 into XOR-swizzled LDS; B-frags straight from global Wt (L2-hot).
__global__ __launch_bounds__(256, 2) void k_qkv(
    const float* __restrict__ x, const unsigned short* __restrict__ wt3,
    unsigned short* __restrict__ qo, unsigned short* __restrict__ ko,
    unsigned short* __restrict__ vo) {
  __shared__ u32x4 xs4[32 * 64 * 2 / 16];    // 4KB, [32][64] bf16 swizzled
  char* xs = (char*)xs4;
  const int tid = threadIdx.x;
  const int lane = tid & 63;
  const int w = tid >> 6;
  const int m0 = blockIdx.x * 32;

  const int sr = tid >> 3;                   // staging row 0..31
  const int scb = (tid & 7) * 16;            // staging col byte (8 bf16)
  const float* xp = x + (size_t)(m0 + sr) * NC + (tid & 7) * 8;
  const int wb = (sr * 128 + scb) ^ ((sr & 7) << 4);

  const int arow = lane & 15;
  const int aswz = (arow & 7) << 4;
  const int akb = (lane >> 4) * 16;          // k-group byte offset
  const int n0 = w * 96;                     // wave covers cols n0..n0+95 of 384

  f32x4 acc[2][6] = {};
  f32x4 xa = *(const f32x4*)(xp);
  f32x4 xb = *(const f32x4*)(xp + 4);

  for (int kt = 0; kt < 16; ++kt) {
    __syncthreads();                         // everyone done reading xs
    u32x4 pk = { pack2(xa.x, xa.y), pack2(xa.z, xa.w),
                 pack2(xb.x, xb.y), pack2(xb.z, xb.w) };
    *(u32x4*)(xs + wb) = pk;
    __syncthreads();
    if (kt < 15) {                           // prefetch next x tile (hidden by compute)
      xa = *(const f32x4*)(xp + (kt + 1) * 64);
      xb = *(const f32x4*)(xp + (kt + 1) * 64 + 4);
    }
    #pragma unroll
    for (int ks = 0; ks < 2; ++ks) {
      s16x8 a0 = *(const s16x8*)(xs + (((arow)      * 128 + ks * 64 + akb) ^ aswz));
      s16x8 a1 = *(const s16x8*)(xs + (((arow + 16) * 128 + ks * 64 + akb) ^ aswz));
      const unsigned short* wp = wt3 + (size_t)(n0 + (lane & 15)) * NC
                                 + kt * 64 + ks * 32 + (lane >> 4) * 8;
      #pragma unroll
      for (int nj = 0; nj < 6; ++nj) {
        s16x8 bf = *(const s16x8*)(wp + (size_t)nj * 16 * NC);
        acc[0][nj] = mfma16(a0, bf, acc[0][nj]);
        acc[1][nj] = mfma16(a1, bf, acc[1][nj]);
      }
    }
  }
  // epilogue: q,k row-major [M][128]; v transposed [B][128][T] (PV wants kv-contiguous)
  const int rl = (lane >> 4) * 4;
  #pragma unroll
  for (int m = 0; m < 2; ++m) {
    #pragma unroll
    for (int nj = 0; nj < 6; ++nj) {
      f32x4 a = acc[m][nj];
      int gcol = n0 + nj * 16 + (lane & 15);
      int gr = m0 + m * 16 + rl;
      int h = gcol & 127;
      if (gcol < 256) {
        unsigned short* dst = (gcol < 128) ? qo : ko;
        dst[(size_t)(gr + 0) * NH + h] = f2bf(a.x);
        dst[(size_t)(gr + 1) * NH + h] = f2bf(a.y);
        dst[(size_t)(gr + 2) * NH + h] = f2bf(a.z);
        dst[(size_t)(gr + 3) * NH + h] = f2bf(a.w);
      } else {
        int bb = gr >> 11, tt = gr & 2047;   // 4 consecutive t -> packed 8B store
        u16x4 pv = { f2bf(a.x), f2bf(a.y), f2bf(a.z), f2bf(a.w) };
        *(u16x4*)(vo + ((size_t)(bb * NH + h) * NT + tt)) = pv;
      }
    }
  }
}

// ---------------- kernel 2: flash attention. 256 blocks = (32 q-tiles, 8 batches).
// 4 waves x 16 q-rows; K/Vt tiles (64 kv) reg-staged into swizzled LDS w/ prefetch.
__global__ __launch_bounds__(256) void k_attn(
    const unsigned short* __restrict__ qg, const unsigned short* __restrict__ kg,
    const unsigned short* __restrict__ vg, float* __restrict__ out) {
  __shared__ u32x4 lds4[40 * 1024 / 16];
  char* Ks = (char*)lds4;                    // [64][128] bf16 swizzled (16KB)
  char* Vs = Ks + 16 * 1024;                 // [128][64] bf16 swizzled (16KB)
  char* Ps = Vs + 16 * 1024;                 // 4 waves x 2KB
  const int tid = threadIdx.x;
  const int lane = tid & 63;
  const int w = tid >> 6;
  const int b = blockIdx.y;
  const int qr = blockIdx.x * 64 + w * 16;
  const int c15 = lane & 15;
  const int g4 = lane >> 4;

  s16x8 qf[4];                               // Q rows in registers, loaded once
  #pragma unroll
  for (int ks = 0; ks < 4; ++ks)
    qf[ks] = *(const s16x8*)(qg + (size_t)(b * NT + qr + c15) * NH + ks * 32 + g4 * 8);

  float m_run[4], l_run[4];
  #pragma unroll
  for (int r = 0; r < 4; ++r) { m_run[r] = -3.0e38f; l_run[r] = 0.0f; }
  f32x4 acc_o[8] = {};

  const int skr = tid >> 4;                  // K staging row base 0..15 (+i*16)
  const unsigned short* kbase = kg + (size_t)b * NT * NH + (tid & 15) * 8;
  const int svh = tid >> 3;                  // V staging h base 0..31 (+i*32)
  const unsigned short* vbase = vg + (size_t)(b * NH) * NT + (tid & 7) * 8;

  u32x4 kreg[4], vreg[4];
  #pragma unroll
  for (int i = 0; i < 4; ++i) {
    kreg[i] = *(const u32x4*)(kbase + (size_t)(skr + i * 16) * NH);
    vreg[i] = *(const u32x4*)(vbase + (size_t)(svh + i * 32) * NT);
  }
  auto write_tiles = [&]() {
    #pragma unroll
    for (int i = 0; i < 4; ++i) {
      int r = skr + i * 16;
      *(u32x4*)(Ks + ((r * 256 + (tid & 15) * 16) ^ ((r & 7) << 4))) = kreg[i];
      int h = svh + i * 32;
      *(u32x4*)(Vs + ((h * 128 + (tid & 7) * 16) ^ ((h & 7) << 4))) = vreg[i];
    }
  };
  write_tiles();
  __syncthreads();

  char* pw = Ps + w * 2048;

  for (int kt = 0; kt < 32; ++kt) {
    if (kt < 31) {                           // issue next tile's loads early (T14)
      #pragma unroll
      for (int i = 0; i < 4; ++i) {
        kreg[i] = *(const u32x4*)(kbase + (size_t)((kt + 1) * 64 + skr + i * 16) * NH);
        vreg[i] = *(const u32x4*)(vbase + (size_t)(svh + i * 32) * NT + (kt + 1) * 64);
      }
    }
    // S = Q K^T  (scale pre-folded into Wq)
    f32x4 s[4] = {};
    #pragma unroll
    for (int nj = 0; nj < 4; ++nj) {
      int krow = nj * 16 + c15;
      int kswz = (krow & 7) << 4;
      #pragma unroll
      for (int ks = 0; ks < 4; ++ks) {
        s16x8 bf = *(const s16x8*)(Ks + ((krow * 256 + ks * 64 + g4 * 16) ^ kswz));
        s[nj] = mfma16(qf[ks], bf, s[nj]);
      }
    }
    // online softmax; row data lives in the 16-lane group sharing g4
    float alpha[4];
    #pragma unroll
    for (int r = 0; r < 4; ++r) {
      float pm = fmaxf(fmaxf(s[0][r], s[1][r]), fmaxf(s[2][r], s[3][r]));
      pm = fmaxf(pm, __shfl_xor(pm, 1));
      pm = fmaxf(pm, __shfl_xor(pm, 2));
      pm = fmaxf(pm, __shfl_xor(pm, 4));
      pm = fmaxf(pm, __shfl_xor(pm, 8));
      float mn = fmaxf(m_run[r], pm);
      alpha[r] = __expf(m_run[r] - mn);
      m_run[r] = mn;
      float e0 = __expf(s[0][r] - mn);
      float e1 = __expf(s[1][r] - mn);
      float e2 = __expf(s[2][r] - mn);
      float e3 = __expf(s[3][r] - mn);
      s[0][r] = e0; s[1][r] = e1; s[2][r] = e2; s[3][r] = e3;
      float ps = e0 + e1 + e2 + e3;
      ps += __shfl_xor(ps, 1);
      ps += __shfl_xor(ps, 2);
      ps += __shfl_xor(ps, 4);
      ps += __shfl_xor(ps, 8);
      l_run[r] = l_run[r] * alpha[r] + ps;
    }
    #pragma unroll
    for (int hj = 0; hj < 8; ++hj) {
      acc_o[hj][0] *= alpha[0]; acc_o[hj][1] *= alpha[1];
      acc_o[hj][2] *= alpha[2]; acc_o[hj][3] *= alpha[3];
    }
    // P -> per-wave LDS (reshape to A-fragment layout); wave-local, no barrier
    #pragma unroll
    for (int nj = 0; nj < 4; ++nj) {
      int colb = (nj * 16 + c15) * 2;
      #pragma unroll
      for (int r = 0; r < 4; ++r) {
        int row = g4 * 4 + r;
        *(unsigned short*)(pw + ((row * 128 + colb) ^ ((row & 7) << 4))) = f2bf(s[nj][r]);
      }
    }
    // O += P V
    #pragma unroll
    for (int ks2 = 0; ks2 < 2; ++ks2) {
      s16x8 pa = *(const s16x8*)(pw + ((c15 * 128 + ks2 * 64 + g4 * 16) ^ ((c15 & 7) << 4)));
      #pragma unroll
      for (int hj = 0; hj < 8; ++hj) {
        int vrow = hj * 16 + c15;
        s16x8 bv = *(const s16x8*)(Vs + ((vrow * 128 + ks2 * 64 + g4 * 16) ^ ((vrow & 7) << 4)));
        acc_o[hj] = mfma16(pa, bv, acc_o[hj]);
      }
    }
    __syncthreads();                         // all waves done reading Ks/Vs
    if (kt < 31) write_tiles();              // compiler waits vmcnt for kreg/vreg
    __syncthreads();
  }
  float inv[4];
  #pragma unroll
  for (int r = 0; r < 4; ++r) inv[r] = 1.0f / l_run[r];
  #pragma unroll
  for (int hj = 0; hj < 8; ++hj) {
    int h = hj * 16 + c15;
    #pragma unroll
    for (int r = 0; r < 4; ++r) {
      int t = qr + g4 * 4 + r;
      out[(size_t)(b * NT + t) * NH + h] = acc_o[hj][r] * inv[r];
    }
  }
}

extern "C" void kernel_launch(void* const* d_in, const int* in_sizes, int n_in,
                              void* d_out, int out_size, void* d_ws, size_t ws_size,
                              hipStream_t stream) {
  const float* x  = (const float*)d_in[0];
  const float* wq = (const float*)d_in[1];
  const float* wk = (const float*)d_in[2];
  const float* wv = (const float*)d_in[3];
  unsigned short* ws  = (unsigned short*)d_ws;
  unsigned short* qb  = ws;                          // [M][128] bf16   (4MB)
  unsigned short* kb  = ws + (size_t)2 * 1024 * 1024; // [M][128] bf16  (4MB)
  unsigned short* vb  = ws + (size_t)4 * 1024 * 1024; // [B][128][T] bf16 (4MB)
  unsigned short* wt3 = ws + (size_t)6 * 1024 * 1024; // [3][128][1024] bf16 (0.75MB)

  k_prep_w<<<dim3(1536), dim3(256), 0, stream>>>(wq, wk, wv, wt3);
  k_qkv<<<dim3(NM / 32), dim3(256), 0, stream>>>(x, wt3, qb, kb, vb);
  k_attn<<<dim3(NT / 64, NB), dim3(256), 0, stream>>>(qb, kb, vb, (float*)d_out);
}

// Round 3
// 189.327 us; speedup vs baseline: 1.1567x; 1.1567x over previous
//
#include <hip/hip_runtime.h>

typedef __attribute__((ext_vector_type(4))) float  f32x4;
typedef __attribute__((ext_vector_type(8))) short  s16x8;
typedef __attribute__((ext_vector_type(4))) unsigned int u32x4;
typedef __attribute__((ext_vector_type(4))) unsigned short u16x4;

#define NB 8
#define NT 2048
#define NC 1024
#define NH 128
#define NM (NB * NT)

__device__ __forceinline__ unsigned short f2bf(float f) {
  union { float f; unsigned u; } v; v.f = f;
  unsigned r = v.u + 0x7FFFu + ((v.u >> 16) & 1u);  // RNE
  return (unsigned short)(r >> 16);
}
__device__ __forceinline__ unsigned pack2(float a, float b) {
  return (unsigned)f2bf(a) | ((unsigned)f2bf(b) << 16);
}
__device__ __forceinline__ f32x4 mfma16(s16x8 a, s16x8 b, f32x4 c) {
  return __builtin_amdgcn_mfma_f32_16x16x32_bf16(a, b, c, 0, 0, 0);
}

// ---------------- kernel 0: W -> bf16 transposed [3][128][1024], both sides coalesced
// via 64x64 LDS tile. Wq pre-scaled by 1/sqrt(128).
__global__ __launch_bounds__(256) void k_prep_w(
    const float* __restrict__ wq, const float* __restrict__ wk,
    const float* __restrict__ wv, unsigned short* __restrict__ wt3) {
  __shared__ float ts[64][65];               // +1 pad: conflict-free transpose
  const int tid = threadIdx.x;
  const int w = blockIdx.x >> 5;             // 0..2 (matrix)
  const int rem = blockIdx.x & 31;
  const int c0 = (rem >> 1) * 64;            // 16 c-tiles
  const int h0 = (rem & 1) * 64;             // 2 h-tiles
  const float* W = (w == 0) ? wq : (w == 1) ? wk : wv;
  const int hl = tid & 63, ci = tid >> 6;
  #pragma unroll
  for (int i = 0; i < 16; ++i) {
    int cl = i * 4 + ci;
    ts[cl][hl] = W[(size_t)(c0 + cl) * NH + h0 + hl];   // 256B/row coalesced
  }
  __syncthreads();
  const int cl2 = tid & 63, hi2 = tid >> 6;
  #pragma unroll
  for (int j = 0; j < 16; ++j) {
    int hl2 = j * 4 + hi2;
    float v = ts[cl2][hl2];
    if (w == 0) v *= 0.08838834764831845f;
    wt3[(size_t)w * 131072 + (size_t)(h0 + hl2) * NC + c0 + cl2] = f2bf(v);  // 128B coalesced
  }
}

// ---------------- kernel 1: q,k,v projections. BM=64, 8 waves (512 thr), dbuf LDS,
// 1 barrier/iter. B-frags straight from global Wt (L2-hot, halved vs BM=32).
__global__ __launch_bounds__(512) void k_qkv(
    const float* __restrict__ x, const unsigned short* __restrict__ wt3,
    unsigned short* __restrict__ qo, unsigned short* __restrict__ ko,
    unsigned short* __restrict__ vo) {
  __shared__ u32x4 xs4[2 * 64 * 128 / 16];   // 16KB: 2 bufs x [64 rows][128B] swizzled
  char* xs = (char*)xs4;
  const int tid = threadIdx.x;
  const int lane = tid & 63;
  const int w = tid >> 6;                    // 0..7
  const int m0 = blockIdx.x * 64;

  const int sr = tid >> 3;                   // staging row 0..63
  const float* xp = x + (size_t)(m0 + sr) * NC + (tid & 7) * 8;
  const int wb = (sr * 128 + (tid & 7) * 16) ^ ((sr & 7) << 4);

  const int mg = w >> 2;                     // m-half
  const int n0 = (w & 3) * 96;               // n-strip
  const int arow0 = mg * 32 + (lane & 15);
  const int aswz = (arow0 & 7) << 4;         // same for arow0+16
  const int akb = (lane >> 4) * 16;

  f32x4 acc[2][6] = {};
  f32x4 xa = *(const f32x4*)(xp);
  f32x4 xb = *(const f32x4*)(xp + 4);
  {
    u32x4 pk = { pack2(xa.x, xa.y), pack2(xa.z, xa.w),
                 pack2(xb.x, xb.y), pack2(xb.z, xb.w) };
    *(u32x4*)(xs + wb) = pk;                 // buf 0
  }
  __syncthreads();

  for (int kt = 0; kt < 16; ++kt) {
    if (kt < 15) {                           // prefetch next x tile into regs
      xa = *(const f32x4*)(xp + (kt + 1) * 64);
      xb = *(const f32x4*)(xp + (kt + 1) * 64 + 4);
    }
    char* cb = xs + (kt & 1) * 8192;
    #pragma unroll
    for (int ks = 0; ks < 2; ++ks) {
      s16x8 a0 = *(const s16x8*)(cb + (((arow0)      * 128 + ks * 64 + akb) ^ aswz));
      s16x8 a1 = *(const s16x8*)(cb + (((arow0 + 16) * 128 + ks * 64 + akb) ^ aswz));
      const unsigned short* wp = wt3 + (size_t)(n0 + (lane & 15)) * NC
                                 + kt * 64 + ks * 32 + (lane >> 4) * 8;
      #pragma unroll
      for (int nj = 0; nj < 6; ++nj) {
        s16x8 bf = *(const s16x8*)(wp + (size_t)nj * 16 * NC);
        acc[0][nj] = mfma16(a0, bf, acc[0][nj]);
        acc[1][nj] = mfma16(a1, bf, acc[1][nj]);
      }
    }
    if (kt < 15) {                           // write next tile to other buf
      u32x4 pk = { pack2(xa.x, xa.y), pack2(xa.z, xa.w),
                   pack2(xb.x, xb.y), pack2(xb.z, xb.w) };
      *(u32x4*)(xs + ((kt + 1) & 1) * 8192 + wb) = pk;
    }
    __syncthreads();                         // single barrier per iter (dbuf)
  }
  // epilogue: q,k row-major [M][128]; v transposed [B][128][T]
  const int rl = (lane >> 4) * 4;
  #pragma unroll
  for (int m = 0; m < 2; ++m) {
    #pragma unroll
    for (int nj = 0; nj < 6; ++nj) {
      f32x4 a = acc[m][nj];
      int gcol = n0 + nj * 16 + (lane & 15);
      int gr = m0 + mg * 32 + m * 16 + rl;
      int h = gcol & 127;
      if (gcol < 256) {
        unsigned short* dst = (gcol < 128) ? qo : ko;
        dst[(size_t)(gr + 0) * NH + h] = f2bf(a.x);
        dst[(size_t)(gr + 1) * NH + h] = f2bf(a.y);
        dst[(size_t)(gr + 2) * NH + h] = f2bf(a.z);
        dst[(size_t)(gr + 3) * NH + h] = f2bf(a.w);
      } else {
        int bb = gr >> 11, tt = gr & 2047;
        u16x4 pv = { f2bf(a.x), f2bf(a.y), f2bf(a.z), f2bf(a.w) };
        *(u16x4*)(vo + ((size_t)(bb * NH + h) * NT + tt)) = pv;
      }
    }
  }
}

// ---------------- kernel 2: flash attention, in-block kv-split.
// 512 thr = 2 groups x 4 waves; group g owns kv half [g*1024, g*1024+1024).
// Each group: dbuf K/V LDS (1 barrier/iter), deferred l-reduce, LDS merge at end.
__global__ __launch_bounds__(512) void k_attn(
    const unsigned short* __restrict__ qg, const unsigned short* __restrict__ kg,
    const unsigned short* __restrict__ vg, float* __restrict__ out) {
  __shared__ u32x4 lds4[147456 / 16];        // 144KB
  char* L = (char*)lds4;
  const int tid = threadIdx.x;
  const int lane = tid & 63;
  const int w = tid >> 6;                    // 0..7
  const int grp = w >> 2;                    // kv half
  const int wq = w & 3;                      // q sub-tile
  const int gt = tid & 255;                  // group-local tid
  const int b = blockIdx.y;
  const int qr = blockIdx.x * 64 + wq * 16;
  const int c15 = lane & 15;
  const int g4 = lane >> 4;
  const int kv0 = grp * 1024;

  char* Kb0 = L + grp * 65536;               // 2 x 16KB K bufs
  char* Vb0 = L + grp * 65536 + 32768;       // 2 x 16KB V bufs
  char* pw  = L + 131072 + w * 2048;         // per-wave P

  s16x8 qf[4];
  #pragma unroll
  for (int ks = 0; ks < 4; ++ks)
    qf[ks] = *(const s16x8*)(qg + (size_t)(b * NT + qr + c15) * NH + ks * 32 + g4 * 8);

  float m_run[4], lsum[4];
  #pragma unroll
  for (int r = 0; r < 4; ++r) { m_run[r] = -3.0e38f; lsum[r] = 0.0f; }
  f32x4 acc_o[8] = {};

  const int skr = gt >> 4;                   // K staging row base
  const unsigned short* kbase = kg + (size_t)(b * NT + kv0) * NH + (gt & 15) * 8;
  const int svh = gt >> 3;                   // V staging h base
  const unsigned short* vbase = vg + (size_t)(b * NH) * NT + kv0 + (gt & 7) * 8;

  u32x4 kreg[4], vreg[4];
  #pragma unroll
  for (int i = 0; i < 4; ++i) {
    kreg[i] = *(const u32x4*)(kbase + (size_t)(skr + i * 16) * NH);
    vreg[i] = *(const u32x4*)(vbase + (size_t)(svh + i * 32) * NT);
  }
  auto write_tiles = [&](char* Kd, char* Vd) {
    #pragma unroll
    for (int i = 0; i < 4; ++i) {
      int r = skr + i * 16;
      *(u32x4*)(Kd + ((r * 256 + (gt & 15) * 16) ^ ((r & 7) << 4))) = kreg[i];
      int h = svh + i * 32;
      *(u32x4*)(Vd + ((h * 128 + (gt & 7) * 16) ^ ((h & 7) << 4))) = vreg[i];
    }
  };
  write_tiles(Kb0, Vb0);
  __syncthreads();

  for (int kt = 0; kt < 16; ++kt) {
    char* Ks = Kb0 + (kt & 1) * 16384;
    char* Vs = Vb0 + (kt & 1) * 16384;
    if (kt < 15) {                           // issue next tile loads early
      #pragma unroll
      for (int i = 0; i < 4; ++i) {
        kreg[i] = *(const u32x4*)(kbase + (size_t)((kt + 1) * 64 + skr + i * 16) * NH);
        vreg[i] = *(const u32x4*)(vbase + (size_t)(svh + i * 32) * NT + (kt + 1) * 64);
      }
    }
    // S = Q K^T
    f32x4 s[4] = {};
    __builtin_amdgcn_s_setprio(1);
    #pragma unroll
    for (int nj = 0; nj < 4; ++nj) {
      int krow = nj * 16 + c15;
      int kswz = (krow & 7) << 4;
      #pragma unroll
      for (int ks = 0; ks < 4; ++ks) {
        s16x8 bf = *(const s16x8*)(Ks + ((krow * 256 + ks * 64 + g4 * 16) ^ kswz));
        s[nj] = mfma16(qf[ks], bf, s[nj]);
      }
    }
    __builtin_amdgcn_s_setprio(0);
    // online softmax: max needs row-reduce (4 shfl); l-sum deferred to end
    float alpha[4];
    #pragma unroll
    for (int r = 0; r < 4; ++r) {
      float pm = fmaxf(fmaxf(s[0][r], s[1][r]), fmaxf(s[2][r], s[3][r]));
      pm = fmaxf(pm, __shfl_xor(pm, 1));
      pm = fmaxf(pm, __shfl_xor(pm, 2));
      pm = fmaxf(pm, __shfl_xor(pm, 4));
      pm = fmaxf(pm, __shfl_xor(pm, 8));
      float mn = fmaxf(m_run[r], pm);
      alpha[r] = __expf(m_run[r] - mn);
      m_run[r] = mn;
      float e0 = __expf(s[0][r] - mn);
      float e1 = __expf(s[1][r] - mn);
      float e2 = __expf(s[2][r] - mn);
      float e3 = __expf(s[3][r] - mn);
      s[0][r] = e0; s[1][r] = e1; s[2][r] = e2; s[3][r] = e3;
      lsum[r] = lsum[r] * alpha[r] + (e0 + e1 + e2 + e3);   // per-lane partial
    }
    #pragma unroll
    for (int hj = 0; hj < 8; ++hj) {
      acc_o[hj][0] *= alpha[0]; acc_o[hj][1] *= alpha[1];
      acc_o[hj][2] *= alpha[2]; acc_o[hj][3] *= alpha[3];
    }
    // P -> per-wave LDS (A-fragment reshape, wave-local)
    #pragma unroll
    for (int nj = 0; nj < 4; ++nj) {
      int colb = (nj * 16 + c15) * 2;
      #pragma unroll
      for (int r = 0; r < 4; ++r) {
        int row = g4 * 4 + r;
        *(unsigned short*)(pw + ((row * 128 + colb) ^ ((row & 7) << 4))) = f2bf(s[nj][r]);
      }
    }
    // O += P V
    __builtin_amdgcn_s_setprio(1);
    #pragma unroll
    for (int ks2 = 0; ks2 < 2; ++ks2) {
      s16x8 pa = *(const s16x8*)(pw + ((c15 * 128 + ks2 * 64 + g4 * 16) ^ ((c15 & 7) << 4)));
      #pragma unroll
      for (int hj = 0; hj < 8; ++hj) {
        int vrow = hj * 16 + c15;
        s16x8 bv = *(const s16x8*)(Vs + ((vrow * 128 + ks2 * 64 + g4 * 16) ^ ((vrow & 7) << 4)));
        acc_o[hj] = mfma16(pa, bv, acc_o[hj]);
      }
    }
    __builtin_amdgcn_s_setprio(0);
    if (kt < 15) write_tiles(Kb0 + ((kt + 1) & 1) * 16384, Vb0 + ((kt + 1) & 1) * 16384);
    __syncthreads();                         // single barrier per iter (dbuf)
  }
  // finish deferred l: reduce across the 16-lane row group
  float l_run[4];
  #pragma unroll
  for (int r = 0; r < 4; ++r) {
    float ls = lsum[r];
    ls += __shfl_xor(ls, 1);
    ls += __shfl_xor(ls, 2);
    ls += __shfl_xor(ls, 4);
    ls += __shfl_xor(ls, 8);
    l_run[r] = ls;
  }
  // merge the two kv-halves through LDS (reuse K/V region; loop ended w/ barrier)
  float* msh = (float*)(L + 32768);
  float* lsh = (float*)(L + 32768 + 256);
  if (grp == 1) {
    #pragma unroll
    for (int r = 0; r < 4; ++r) {
      int row = wq * 16 + g4 * 4 + r;
      #pragma unroll
      for (int hj = 0; hj < 8; ++hj)
        *(float*)(L + ((row * 512 + (hj * 16 + c15) * 4) ^ ((row & 7) << 4))) = acc_o[hj][r];
      if (c15 == 0) { msh[row] = m_run[r]; lsh[row] = l_run[r]; }
    }
  }
  __syncthreads();
  if (grp == 0) {
    #pragma unroll
    for (int r = 0; r < 4; ++r) {
      int row = wq * 16 + g4 * 4 + r;
      float m1 = msh[row], l1 = lsh[row];
      float M = fmaxf(m_run[r], m1);
      float w0 = __expf(m_run[r] - M);
      float w1 = __expf(m1 - M);
      float den = 1.0f / (w0 * l_run[r] + w1 * l1);
      #pragma unroll
      for (int hj = 0; hj < 8; ++hj) {
        float o1 = *(const float*)(L + ((row * 512 + (hj * 16 + c15) * 4) ^ ((row & 7) << 4)));
        out[(size_t)(b * NT + qr + g4 * 4 + r) * NH + hj * 16 + c15] =
            (w0 * acc_o[hj][r] + w1 * o1) * den;
      }
    }
  }
}

extern "C" void kernel_launch(void* const* d_in, const int* in_sizes, int n_in,
                              void* d_out, int out_size, void* d_ws, size_t ws_size,
                              hipStream_t stream) {
  const float* x  = (const float*)d_in[0];
  const float* wq = (const float*)d_in[1];
  const float* wk = (const float*)d_in[2];
  const float* wv = (const float*)d_in[3];
  unsigned short* ws  = (unsigned short*)d_ws;
  unsigned short* qb  = ws;                           // [M][128] bf16   (4MB)
  unsigned short* kb  = ws + (size_t)2 * 1024 * 1024; // [M][128] bf16   (4MB)
  unsigned short* vb  = ws + (size_t)4 * 1024 * 1024; // [B][128][T] bf16 (4MB)
  unsigned short* wt3 = ws + (size_t)6 * 1024 * 1024; // [3][128][1024] bf16 (0.75MB)

  k_prep_w<<<dim3(96), dim3(256), 0, stream>>>(wq, wk, wv, wt3);
  k_qkv<<<dim3(NM / 64), dim3(512), 0, stream>>>(x, wt3, qb, kb, vb);
  k_attn<<<dim3(NT / 64, NB), dim3(512), 0, stream>>>(qb, kb, vb, (float*)d_out);
}